// Round 3
// baseline (394.542 us; speedup 1.0000x reference)
//
#include <hip/hip_runtime.h>
#include <math.h>

// ComplexEMA fused single-kernel (R5 = R4 with the LDS Hillis-Steele replaced
// by a wave-synchronous shuffle scan).
// y[b,d,t] = Re(sum_n gam_dn * h_dn[t]) + omega_d * x[b,d,t]
// h[t] = q*h[t-1] + p*x[t];  substitution u = h/p:  u' = q*u + x, gam' = p*gam.
//
// One block (128 threads = 2 waves) per (b,d) row; each thread owns a 32-step
// chunk. x is staged ONCE from HBM via 128B/lane bursts into a conflict-free
// SoA LDS buffer xls[j][tid] (lane-consecutive banks, 2-way = free).
// Phase 1: local chunk recurrence from zero -> chunk end-state F (16 complex).
// Scan:    6-step __shfl_up Hillis-Steele within each wave (A = q^32 doubling)
//          -- no LDS, no barriers, no bank conflicts. Wave 1 additionally
//          accumulates W = A^(llane+1) from the same doubled multipliers,
//          then applies the cross-wave correction  u += W * U0[63]  after a
//          single 128B LDS publish + barrier (2 barriers total in kernel,
//          was 15 in R4; R4 counters: 1.83M conflict cycles, VALUBusy 56%).
// Phase 3: re-run chunk from exclusive prefix (shfl_up by 1), emit y with
//          128B/lane burst stores.

constexpr int kD = 2048, kN = 16, kB = 2, kL = 4096;
constexpr int kT  = 128;            // threads (= chunks) per row, 2 waves
constexpr int kCH = kL / kT;        // 32 timesteps per thread
constexpr float kSCALE = 0.25f;     // sqrt(1/16)

typedef float v2 __attribute__((ext_vector_type(2)));

static __device__ __forceinline__ v2 mkv2(float a, float b) {
    v2 r; r.x = a; r.y = b; return r;
}

static __device__ __forceinline__ v2 v2fma(v2 a, v2 b, v2 c) {
#if __has_builtin(__builtin_elementwise_fma)
    return __builtin_elementwise_fma(a, b, c);
#else
    v2 r;
    r.x = __builtin_fmaf(a.x, b.x, c.x);
    r.y = __builtin_fmaf(a.y, b.y, c.y);
    return r;
#endif
}

__global__ __launch_bounds__(kT, 4) void fused_kernel(
    const float* __restrict__ x,     const float* __restrict__ alpha,
    const float* __restrict__ delta, const float* __restrict__ theta,
    const float* __restrict__ gamma, const float* __restrict__ omega,
    float* __restrict__ y,           float* __restrict__ hout)
{
    // x staging, SoA layout [j][tid]: per-j access is lane-consecutive -> no
    // bank conflicts. 16 KB.
    __shared__ float xls[kCH * kT];
    __shared__ float cqr[kN], cqi[kN], cgr[kN], cgi[kN], cp[kN];
    __shared__ float pubr[kN], pubi[kN];   // wave-0 final state publish

    const int row   = blockIdx.x;        // b*kD + d
    const int d     = row & (kD - 1);
    const int tid   = threadIdx.x;
    const int llane = tid & 63;

    // --- burst-load this thread's 32 x samples (8 back-to-back dwordx4 =
    //     128 B/lane, full-line coverage) then scatter to SoA LDS.
    const float4* xp = (const float4*)(x + (size_t)row * kL + (size_t)tid * kCH);
    float4 tb[8];
#pragma unroll
    for (int k = 0; k < 8; k++) tb[k] = xp[k];
#pragma unroll
    for (int k = 0; k < 8; k++) {
        xls[(4 * k + 0) * kT + tid] = tb[k].x;
        xls[(4 * k + 1) * kT + tid] = tb[k].y;
        xls[(4 * k + 2) * kT + tid] = tb[k].z;
        xls[(4 * k + 3) * kT + tid] = tb[k].w;
    }

    // --- coefficients (threads 0..15, one n each)
    if (tid < kN) {
        int n = tid, i = d * kN + n;
        float p  = 1.0f / (1.0f + expf(-alpha[i]));
        float dd = 1.0f / (1.0f + expf(-delta[i]));
        float th = 1.0f / (1.0f + expf(-theta[d]));
        float phi = (float)(n + 1) * th * 0.39269908169872414f;  // 2*pi/16
        float r = 1.0f - p * dd;
        float s, c;
        sincosf(phi, &s, &c);
        cqr[n] = r * c;
        cqi[n] = r * s;
        cgr[n] = p * kSCALE * gamma[2 * i];
        cgi[n] = -(p * kSCALE * gamma[2 * i + 1]);
        cp[n]  = p;
    }
    __syncthreads();                      // barrier #1 (coeff visibility)

    // --- phase 1: local recurrence from zero init (first step peeled).
    {
        v2 qx[kN], qy[kN];
#pragma unroll
        for (int n = 0; n < kN; n++) {
            qx[n] = mkv2(cqr[n],  cqr[n]);
            qy[n] = mkv2(-cqi[n], cqi[n]);
        }
        v2 u0[kN];
        float x0 = xls[tid];
#pragma unroll
        for (int n = 0; n < kN; n++) u0[n] = mkv2(x0, 0.0f);
#pragma unroll
        for (int j = 1; j < kCH; j++) {
            v2 xv = mkv2(xls[j * kT + tid], 0.0f);
#pragma unroll
            for (int n = 0; n < kN; n++) {
                v2 a  = v2fma(qx[n], u0[n], xv);
                u0[n] = v2fma(qy[n], mkv2(u0[n].y, u0[n].x), a);
            }
        }
        // fallthrough: u0 lives on as 'u' below
#pragma unroll
        for (int n = 0; n < kN; n++) qx[n] = u0[n];  // keep in qx slot
        // (compiler coalesces; semantic copy only)
        __builtin_memcpy(nullptr, nullptr, 0);       // no-op
        // move to outer-scope u
        // (we just re-declare below using qx values)
        v2* dummy = nullptr; (void)dummy;
        // -- handled by structured code below --
        // (see 'u' declaration)
        // NOTE: restructured without the extra copy:
        goto after_phase1;               // placeholder never taken
    after_phase1:;
        // store into block-scope u
        // (actual code continues outside this block)
        // -- we instead write phase 1 directly on 'u' --
        (void)0;
    }

    // The block above was structured poorly for register reuse; real phase-1
    // implementation (on 'u' directly):
    v2 u[kN];
    {
        v2 qx[kN], qy[kN];
#pragma unroll
        for (int n = 0; n < kN; n++) {
            qx[n] = mkv2(cqr[n],  cqr[n]);
            qy[n] = mkv2(-cqi[n], cqi[n]);
        }
        float x0 = xls[tid];
#pragma unroll
        for (int n = 0; n < kN; n++) u[n] = mkv2(x0, 0.0f);
#pragma unroll
        for (int j = 1; j < kCH; j++) {
            v2 xv = mkv2(xls[j * kT + tid], 0.0f);
#pragma unroll
            for (int n = 0; n < kN; n++) {
                v2 a = v2fma(qx[n], u[n], xv);
                u[n] = v2fma(qy[n], mkv2(u[n].y, u[n].x), a);
            }
        }
    }

    // --- A = q^32 via 5 complex squarings
    v2 m[kN];
#pragma unroll
    for (int n = 0; n < kN; n++) m[n] = mkv2(cqr[n], cqi[n]);
#pragma unroll
    for (int k = 0; k < 5; k++) {
#pragma unroll
        for (int n = 0; n < kN; n++) {
            float mr = m[n].x, mi = m[n].y;
            m[n] = mkv2(__builtin_fmaf(mr, mr, -(mi * mi)), 2.0f * mr * mi);
        }
    }

    // --- wave-synchronous Hillis-Steele over the 64 lanes of each wave.
    //     Wave 1 accumulates W = A^(llane+1) for the cross-wave correction.
    const bool w1 = (tid >= 64);
    v2 W[kN];
#pragma unroll
    for (int n = 0; n < kN; n++) W[n] = m[n];     // A^1
#pragma unroll
    for (int k = 0; k < 6; k++) {
        const int s = 1 << k;
#pragma unroll
        for (int n = 0; n < kN; n++) {
            float tr = __shfl_up(u[n].x, (unsigned)s, 64);
            float ti = __shfl_up(u[n].y, (unsigned)s, 64);
            if (llane >= s) {
                u[n].x = __builtin_fmaf(m[n].x, tr,
                          __builtin_fmaf(-m[n].y, ti, u[n].x));
                u[n].y = __builtin_fmaf(m[n].x, ti,
                          __builtin_fmaf( m[n].y, tr, u[n].y));
            }
        }
        if (w1 && (llane & s)) {
#pragma unroll
            for (int n = 0; n < kN; n++) {
                float wr = W[n].x, wi = W[n].y;
                W[n].x = __builtin_fmaf(wr, m[n].x, -(wi * m[n].y));
                W[n].y = __builtin_fmaf(wr, m[n].y,  wi * m[n].x);
            }
        }
#pragma unroll
        for (int n = 0; n < kN; n++) {
            float mr = m[n].x, mi = m[n].y;
            m[n] = mkv2(__builtin_fmaf(mr, mr, -(mi * mi)), 2.0f * mr * mi);
        }
    }

    // --- cross-wave combine: publish wave-0 final (lane 63), one barrier.
    if (tid == 63) {
#pragma unroll
        for (int n = 0; n < kN; n++) { pubr[n] = u[n].x; pubi[n] = u[n].y; }
    }
    __syncthreads();                      // barrier #2
    if (w1) {
#pragma unroll
        for (int n = 0; n < kN; n++) {
            float pr = pubr[n], pi = pubi[n];
            u[n].x = __builtin_fmaf(W[n].x, pr,
                      __builtin_fmaf(-W[n].y, pi, u[n].x));
            u[n].y = __builtin_fmaf(W[n].x, pi,
                      __builtin_fmaf( W[n].y, pr, u[n].y));
        }
    }

    // --- final state (tid 127 inclusive) -> hout, h = p*u
    if (tid == kT - 1) {
        float4* hp = (float4*)(hout + (size_t)row * (kN * 2));
#pragma unroll
        for (int n = 0; n < kN; n += 2)
            hp[n >> 1] = make_float4(cp[n] * u[n].x,     cp[n] * u[n].y,
                                     cp[n + 1] * u[n + 1].x, cp[n + 1] * u[n + 1].y);
    }

    // --- exclusive prefix: shift down by one lane; lane 0 of wave 1 takes
    //     wave 0's published final; lane 0 of wave 0 takes zero.
#pragma unroll
    for (int n = 0; n < kN; n++) {
        float pr = __shfl_up(u[n].x, 1, 64);
        float pi = __shfl_up(u[n].y, 1, 64);
        u[n] = mkv2(pr, pi);
    }
    if (llane == 0) {
        if (tid == 0) {
#pragma unroll
            for (int n = 0; n < kN; n++) u[n] = mkv2(0.0f, 0.0f);
        } else {
#pragma unroll
            for (int n = 0; n < kN; n++) u[n] = mkv2(pubr[n], pubi[n]);
        }
    }

    // --- phase 3: re-run chunk from correct init, emit y
    v2 qx[kN], qy[kN], g[kN];
#pragma unroll
    for (int n = 0; n < kN; n++) {
        qx[n] = mkv2(cqr[n],  cqr[n]);
        qy[n] = mkv2(-cqi[n], cqi[n]);
        g[n]  = mkv2(cgr[n],  cgi[n]);
    }
    const float om = omega[d];

    float ys[kCH];
#pragma unroll
    for (int j = 0; j < kCH; j++) {
        float xj = xls[j * kT + tid];
        v2 xv = mkv2(xj, 0.0f);
        v2 acc0 = mkv2(0.0f, 0.0f), acc1 = mkv2(0.0f, 0.0f);
        v2 acc2 = mkv2(0.0f, 0.0f), acc3 = mkv2(0.0f, 0.0f);
#pragma unroll
        for (int n = 0; n < kN; n += 4) {
            v2 a;
            a = v2fma(qx[n],   u[n],   xv);
            u[n]   = v2fma(qy[n],   mkv2(u[n].y,   u[n].x),   a);
            acc0   = v2fma(g[n],    u[n],   acc0);
            a = v2fma(qx[n+1], u[n+1], xv);
            u[n+1] = v2fma(qy[n+1], mkv2(u[n+1].y, u[n+1].x), a);
            acc1   = v2fma(g[n+1],  u[n+1], acc1);
            a = v2fma(qx[n+2], u[n+2], xv);
            u[n+2] = v2fma(qy[n+2], mkv2(u[n+2].y, u[n+2].x), a);
            acc2   = v2fma(g[n+2],  u[n+2], acc2);
            a = v2fma(qx[n+3], u[n+3], xv);
            u[n+3] = v2fma(qy[n+3], mkv2(u[n+3].y, u[n+3].x), a);
            acc3   = v2fma(g[n+3],  u[n+3], acc3);
        }
        v2 s = (acc0 + acc1) + (acc2 + acc3);
        ys[j] = s.x + s.y + om * xj;
    }

    // burst stores (8 back-to-back dwordx4 = 128 B/lane)
    float4* yp = (float4*)(y + (size_t)row * kL + (size_t)tid * kCH);
#pragma unroll
    for (int k = 0; k < 8; k++)
        yp[k] = make_float4(ys[4*k+0], ys[4*k+1], ys[4*k+2], ys[4*k+3]);
}

extern "C" void kernel_launch(void* const* d_in, const int* in_sizes, int n_in,
                              void* d_out, int out_size, void* d_ws, size_t ws_size,
                              hipStream_t stream) {
    const float* x     = (const float*)d_in[0];
    const float* alpha = (const float*)d_in[1];
    const float* delta = (const float*)d_in[2];
    const float* theta = (const float*)d_in[3];
    const float* gamma = (const float*)d_in[4];
    const float* omega = (const float*)d_in[5];
    float* y    = (float*)d_out;
    float* hout = y + (size_t)kB * kD * kL;      // (B,D,N,2) after y

    fused_kernel<<<kB * kD, kT, 0, stream>>>(x, alpha, delta, theta, gamma,
                                             omega, y, hout);
}

// Round 4
// 191.365 us; speedup vs baseline: 2.0617x; 2.0617x over previous
//
#include <hip/hip_runtime.h>
#include <math.h>

// ComplexEMA fused single-kernel (R6 = clean rewrite of the R5 idea).
// y[b,d,t] = Re(sum_n gam_dn * h_dn[t]) + omega_d * x[b,d,t]
// h[t] = q*h[t-1] + p*x[t];  substitution u = h/p:  u' = q*u + x, gam' = p*gam.
//
// One block (128 threads = 2 waves) per (b,d) row; each thread owns a 32-step
// chunk. x is read ONCE from HBM via 128B/lane bursts and staged in a
// conflict-free SoA LDS buffer xls[j][tid] (lane-consecutive -> 2-way = free),
// freeing 32 VGPRs of x state during the scan (R5 spilled: VGPR=64, 693MB
// scratch writes; R6 keeps scan liveness ~96 + temps under launch_bounds(128,2),
// the config that gave spill-free VGPR=120 in R4).
// Phase 1: local chunk recurrence from zero -> chunk end-state (16 complex).
// Scan:    6-step __shfl_up Hillis-Steele within each wave (A = q^32 doubling)
//          -- in-register, no barriers, no bank conflicts (R4's LDS scan cost
//          1.83M conflict cycles + 14 barriers). Wave 1 also accumulates
//          W = A^(llane+1); after ONE 128B LDS publish + barrier it applies
//          the cross-wave correction u += W * U0[63].
// Phase 3: re-run chunk from exclusive prefix (shfl_up 1), emit y bursts.

constexpr int kD = 2048, kN = 16, kB = 2, kL = 4096;
constexpr int kT  = 128;            // threads (= chunks) per row, 2 waves
constexpr int kCH = kL / kT;        // 32 timesteps per thread
constexpr float kSCALE = 0.25f;     // sqrt(1/16)

typedef float v2 __attribute__((ext_vector_type(2)));

static __device__ __forceinline__ v2 mkv2(float a, float b) {
    v2 r; r.x = a; r.y = b; return r;
}

static __device__ __forceinline__ v2 v2fma(v2 a, v2 b, v2 c) {
#if __has_builtin(__builtin_elementwise_fma)
    return __builtin_elementwise_fma(a, b, c);
#else
    v2 r;
    r.x = __builtin_fmaf(a.x, b.x, c.x);
    r.y = __builtin_fmaf(a.y, b.y, c.y);
    return r;
#endif
}

__global__ __launch_bounds__(kT, 2) void fused_kernel(
    const float* __restrict__ x,     const float* __restrict__ alpha,
    const float* __restrict__ delta, const float* __restrict__ theta,
    const float* __restrict__ gamma, const float* __restrict__ omega,
    float* __restrict__ y,           float* __restrict__ hout)
{
    __shared__ float xls[kCH * kT];        // SoA x stage, 16 KB
    __shared__ float cqr[kN], cqi[kN], cgr[kN], cgi[kN], cp[kN];
    __shared__ float pubr[kN], pubi[kN];   // wave-0 final state publish

    const int row   = blockIdx.x;          // b*kD + d
    const int d     = row & (kD - 1);
    const int tid   = threadIdx.x;
    const int llane = tid & 63;

    // --- burst-load 32 x samples (8 back-to-back dwordx4 = 128 B/lane),
    //     scatter to SoA LDS. Loads issued first; latency hides under coeffs.
    const float4* xp = (const float4*)(x + (size_t)row * kL + (size_t)tid * kCH);
    float4 tb[8];
#pragma unroll
    for (int k = 0; k < 8; k++) tb[k] = xp[k];

    // --- coefficients (threads 0..15, one n each)
    if (tid < kN) {
        int n = tid, i = d * kN + n;
        float p  = 1.0f / (1.0f + expf(-alpha[i]));
        float dd = 1.0f / (1.0f + expf(-delta[i]));
        float th = 1.0f / (1.0f + expf(-theta[d]));
        float phi = (float)(n + 1) * th * 0.39269908169872414f;  // 2*pi/16
        float r = 1.0f - p * dd;
        float s, c;
        sincosf(phi, &s, &c);
        cqr[n] = r * c;
        cqi[n] = r * s;
        cgr[n] = p * kSCALE * gamma[2 * i];
        cgi[n] = -(p * kSCALE * gamma[2 * i + 1]);
        cp[n]  = p;
    }

#pragma unroll
    for (int k = 0; k < 8; k++) {
        xls[(4 * k + 0) * kT + tid] = tb[k].x;
        xls[(4 * k + 1) * kT + tid] = tb[k].y;
        xls[(4 * k + 2) * kT + tid] = tb[k].z;
        xls[(4 * k + 3) * kT + tid] = tb[k].w;
    }
    __syncthreads();                       // barrier #1 (coeffs + x stage)

    // --- phase 1: local recurrence from zero init (first step peeled:
    //     u = q*0 + x0 = (x0, 0)).
    v2 u[kN];
    {
        v2 qx[kN], qy[kN];
#pragma unroll
        for (int n = 0; n < kN; n++) {
            qx[n] = mkv2(cqr[n],  cqr[n]);
            qy[n] = mkv2(-cqi[n], cqi[n]);
        }
        float x0 = xls[tid];
#pragma unroll
        for (int n = 0; n < kN; n++) u[n] = mkv2(x0, 0.0f);
#pragma unroll
        for (int j = 1; j < kCH; j++) {
            v2 xv = mkv2(xls[j * kT + tid], 0.0f);
#pragma unroll
            for (int n = 0; n < kN; n++) {
                v2 a = v2fma(qx[n], u[n], xv);
                u[n] = v2fma(qy[n], mkv2(u[n].y, u[n].x), a);
            }
        }
    }   // qx/qy dead here; rebuilt from LDS for phase 3

    // --- A = q^32 via 5 complex squarings
    v2 m[kN];
#pragma unroll
    for (int n = 0; n < kN; n++) m[n] = mkv2(cqr[n], cqi[n]);
#pragma unroll
    for (int k = 0; k < 5; k++) {
#pragma unroll
        for (int n = 0; n < kN; n++) {
            float mr = m[n].x, mi = m[n].y;
            m[n] = mkv2(__builtin_fmaf(mr, mr, -(mi * mi)), 2.0f * mr * mi);
        }
    }

    // --- wave-synchronous Hillis-Steele over 64 lanes (in-register).
    //     Wave 1 accumulates W = A^(llane+1) for the cross-wave correction.
    const bool w1 = (tid >= 64);
    v2 W[kN];
#pragma unroll
    for (int n = 0; n < kN; n++) W[n] = m[n];     // A^1
#pragma unroll
    for (int k = 0; k < 6; k++) {
        const int s = 1 << k;
#pragma unroll
        for (int n = 0; n < kN; n++) {
            float tr = __shfl_up(u[n].x, (unsigned)s, 64);
            float ti = __shfl_up(u[n].y, (unsigned)s, 64);
            if (llane >= s) {
                u[n].x = __builtin_fmaf(m[n].x, tr,
                          __builtin_fmaf(-m[n].y, ti, u[n].x));
                u[n].y = __builtin_fmaf(m[n].x, ti,
                          __builtin_fmaf( m[n].y, tr, u[n].y));
            }
        }
        if (w1 && (llane & s)) {
#pragma unroll
            for (int n = 0; n < kN; n++) {
                float wr = W[n].x, wi = W[n].y;
                W[n].x = __builtin_fmaf(wr, m[n].x, -(wi * m[n].y));
                W[n].y = __builtin_fmaf(wr, m[n].y,  wi * m[n].x);
            }
        }
        if (k < 5) {                       // last squaring unneeded
#pragma unroll
            for (int n = 0; n < kN; n++) {
                float mr = m[n].x, mi = m[n].y;
                m[n] = mkv2(__builtin_fmaf(mr, mr, -(mi * mi)), 2.0f * mr * mi);
            }
        }
    }

    // --- cross-wave combine: publish wave-0 lane-63 state, one barrier.
    if (tid == 63) {
#pragma unroll
        for (int n = 0; n < kN; n++) { pubr[n] = u[n].x; pubi[n] = u[n].y; }
    }
    __syncthreads();                       // barrier #2
    if (w1) {
#pragma unroll
        for (int n = 0; n < kN; n++) {
            float pr = pubr[n], pi = pubi[n];
            u[n].x = __builtin_fmaf(W[n].x, pr,
                      __builtin_fmaf(-W[n].y, pi, u[n].x));
            u[n].y = __builtin_fmaf(W[n].x, pi,
                      __builtin_fmaf( W[n].y, pr, u[n].y));
        }
    }

    // --- final state (tid 127 inclusive) -> hout, h = p*u
    if (tid == kT - 1) {
        float4* hp = (float4*)(hout + (size_t)row * (kN * 2));
#pragma unroll
        for (int n = 0; n < kN; n += 2)
            hp[n >> 1] = make_float4(cp[n] * u[n].x,         cp[n] * u[n].y,
                                     cp[n + 1] * u[n + 1].x, cp[n + 1] * u[n + 1].y);
    }

    // --- exclusive prefix: shift down one lane; lane 0 of wave 1 takes the
    //     published wave-0 final; lane 0 of wave 0 takes zero.
#pragma unroll
    for (int n = 0; n < kN; n++) {
        float pr = __shfl_up(u[n].x, 1, 64);
        float pi = __shfl_up(u[n].y, 1, 64);
        u[n] = mkv2(pr, pi);
    }
    if (llane == 0) {
#pragma unroll
        for (int n = 0; n < kN; n++)
            u[n] = (tid == 0) ? mkv2(0.0f, 0.0f) : mkv2(pubr[n], pubi[n]);
    }

    // --- phase 3: rebuild coefficient regs, re-run chunk, emit y.
    v2 qx[kN], qy[kN], g[kN];
#pragma unroll
    for (int n = 0; n < kN; n++) {
        qx[n] = mkv2(cqr[n],  cqr[n]);
        qy[n] = mkv2(-cqi[n], cqi[n]);
        g[n]  = mkv2(cgr[n],  cgi[n]);
    }
    const float om = omega[d];

    float ys[kCH];
#pragma unroll
    for (int j = 0; j < kCH; j++) {
        float xj = xls[j * kT + tid];
        v2 xv = mkv2(xj, 0.0f);
        v2 acc0 = mkv2(0.0f, 0.0f), acc1 = mkv2(0.0f, 0.0f);
        v2 acc2 = mkv2(0.0f, 0.0f), acc3 = mkv2(0.0f, 0.0f);
#pragma unroll
        for (int n = 0; n < kN; n += 4) {
            v2 a;
            a = v2fma(qx[n],   u[n],   xv);
            u[n]   = v2fma(qy[n],   mkv2(u[n].y,   u[n].x),   a);
            acc0   = v2fma(g[n],    u[n],   acc0);
            a = v2fma(qx[n+1], u[n+1], xv);
            u[n+1] = v2fma(qy[n+1], mkv2(u[n+1].y, u[n+1].x), a);
            acc1   = v2fma(g[n+1],  u[n+1], acc1);
            a = v2fma(qx[n+2], u[n+2], xv);
            u[n+2] = v2fma(qy[n+2], mkv2(u[n+2].y, u[n+2].x), a);
            acc2   = v2fma(g[n+2],  u[n+2], acc2);
            a = v2fma(qx[n+3], u[n+3], xv);
            u[n+3] = v2fma(qy[n+3], mkv2(u[n+3].y, u[n+3].x), a);
            acc3   = v2fma(g[n+3],  u[n+3], acc3);
        }
        v2 s = (acc0 + acc1) + (acc2 + acc3);
        ys[j] = s.x + s.y + om * xj;
    }

    // burst stores (8 back-to-back dwordx4 = 128 B/lane)
    float4* yp = (float4*)(y + (size_t)row * kL + (size_t)tid * kCH);
#pragma unroll
    for (int k = 0; k < 8; k++)
        yp[k] = make_float4(ys[4*k+0], ys[4*k+1], ys[4*k+2], ys[4*k+3]);
}

extern "C" void kernel_launch(void* const* d_in, const int* in_sizes, int n_in,
                              void* d_out, int out_size, void* d_ws, size_t ws_size,
                              hipStream_t stream) {
    const float* x     = (const float*)d_in[0];
    const float* alpha = (const float*)d_in[1];
    const float* delta = (const float*)d_in[2];
    const float* theta = (const float*)d_in[3];
    const float* gamma = (const float*)d_in[4];
    const float* omega = (const float*)d_in[5];
    float* y    = (float*)d_out;
    float* hout = y + (size_t)kB * kD * kL;      // (B,D,N,2) after y

    fused_kernel<<<kB * kD, kT, 0, stream>>>(x, alpha, delta, theta, gamma,
                                             omega, y, hout);
}

// Round 5
// 186.801 us; speedup vs baseline: 2.1121x; 1.0244x over previous
//
#include <hip/hip_runtime.h>
#include <math.h>

// ComplexEMA fused single-kernel (R7 = R4's register-resident x phases +
// R6's in-register shuffle scan; x re-read from global for phase 3).
// y[b,d,t] = Re(sum_n gam_dn * h_dn[t]) + omega_d * x[b,d,t]
// h[t] = q*h[t-1] + p*x[t];  substitution u = h/p:  u' = q*u + x, gam' = p*gam.
//
// Evidence driving this structure:
//  - R4 (x in regs, LDS scan): 95us, VGPR 120, 1.83M conflict cyc, 14 barriers.
//  - R6 (x in LDS, shuffle scan): 110us, 0 conflicts, but +96 LDS ops/thread
//    and ds_read+lgkmcnt inside both dependent loops -> net loss.
//  - FETCH=34MB for a 64MB input => x is L3-resident; re-reading x from
//    global for phase 3 is ~free, so x never needs LDS at all.
// One block (128 threads = 2 waves) per (b,d) row; each thread owns a 32-step
// chunk with its x burst-loaded to REGISTERS (8 dwordx4 = 128B/lane).
// Phase 1: local recurrence from zero -> chunk end-state (16 complex modes).
// Scan:    6-round __shfl_up Hillis-Steele per wave (A=q^32 doubling), W=A^(l+1)
//          on wave 1, ONE LDS publish + barrier for the cross-wave combine.
// Phase 3: x re-loaded from global (issued before the publish barrier so L2/L3
//          latency hides under combine + coeff rebuild), recurrence re-run from
//          the exclusive prefix, y emitted with 128B/lane burst stores.
// LDS = 7*16 floats (~450B) -> LDS never caps occupancy.

constexpr int kD = 2048, kN = 16, kB = 2, kL = 4096;
constexpr int kT  = 128;            // threads (= chunks) per row, 2 waves
constexpr int kCH = kL / kT;        // 32 timesteps per thread
constexpr float kSCALE = 0.25f;     // sqrt(1/16)

typedef float v2 __attribute__((ext_vector_type(2)));

static __device__ __forceinline__ v2 mkv2(float a, float b) {
    v2 r; r.x = a; r.y = b; return r;
}

static __device__ __forceinline__ v2 v2fma(v2 a, v2 b, v2 c) {
#if __has_builtin(__builtin_elementwise_fma)
    return __builtin_elementwise_fma(a, b, c);
#else
    v2 r;
    r.x = __builtin_fmaf(a.x, b.x, c.x);
    r.y = __builtin_fmaf(a.y, b.y, c.y);
    return r;
#endif
}

__global__ __launch_bounds__(kT, 2) void fused_kernel(
    const float* __restrict__ x,     const float* __restrict__ alpha,
    const float* __restrict__ delta, const float* __restrict__ theta,
    const float* __restrict__ gamma, const float* __restrict__ omega,
    float* __restrict__ y,           float* __restrict__ hout)
{
    __shared__ float cqr[kN], cqi[kN], cgr[kN], cgi[kN], cp[kN];
    __shared__ float pubr[kN], pubi[kN];   // wave-0 final state publish

    const int row   = blockIdx.x;          // b*kD + d
    const int d     = row & (kD - 1);
    const int tid   = threadIdx.x;
    const int llane = tid & 63;

    const float4* xp = (const float4*)(x + (size_t)row * kL + (size_t)tid * kCH);

    // --- burst-load 32 x samples to registers (8 back-to-back dwordx4 =
    //     128 B/lane). Issued first; latency hides under coeff compute.
    float xs[kCH];
    {
        float4 tb[8];
#pragma unroll
        for (int k = 0; k < 8; k++) tb[k] = xp[k];
#pragma unroll
        for (int k = 0; k < 8; k++) {
            xs[4*k+0] = tb[k].x; xs[4*k+1] = tb[k].y;
            xs[4*k+2] = tb[k].z; xs[4*k+3] = tb[k].w;
        }
    }

    // --- coefficients (threads 0..15, one n each)
    if (tid < kN) {
        int n = tid, i = d * kN + n;
        float p  = 1.0f / (1.0f + expf(-alpha[i]));
        float dd = 1.0f / (1.0f + expf(-delta[i]));
        float th = 1.0f / (1.0f + expf(-theta[d]));
        float phi = (float)(n + 1) * th * 0.39269908169872414f;  // 2*pi/16
        float r = 1.0f - p * dd;
        float s, c;
        sincosf(phi, &s, &c);
        cqr[n] = r * c;
        cqi[n] = r * s;
        cgr[n] = p * kSCALE * gamma[2 * i];
        cgi[n] = -(p * kSCALE * gamma[2 * i + 1]);
        cp[n]  = p;
    }
    __syncthreads();                       // barrier #1 (coeff visibility)

    // --- phase 1: local recurrence from zero init (first step peeled:
    //     u = q*0 + x0 = (x0, 0)). x consumed from registers.
    v2 u[kN];
    {
        v2 qx[kN], qy[kN];
#pragma unroll
        for (int n = 0; n < kN; n++) {
            qx[n] = mkv2(cqr[n],  cqr[n]);
            qy[n] = mkv2(-cqi[n], cqi[n]);
        }
#pragma unroll
        for (int n = 0; n < kN; n++) u[n] = mkv2(xs[0], 0.0f);
#pragma unroll
        for (int j = 1; j < kCH; j++) {
            v2 xv = mkv2(xs[j], 0.0f);
#pragma unroll
            for (int n = 0; n < kN; n++) {
                v2 a = v2fma(qx[n], u[n], xv);
                u[n] = v2fma(qy[n], mkv2(u[n].y, u[n].x), a);
            }
        }
    }   // qx/qy and xs dead here

    // --- A = q^32 via 5 complex squarings
    v2 m[kN];
#pragma unroll
    for (int n = 0; n < kN; n++) m[n] = mkv2(cqr[n], cqi[n]);
#pragma unroll
    for (int k = 0; k < 5; k++) {
#pragma unroll
        for (int n = 0; n < kN; n++) {
            float mr = m[n].x, mi = m[n].y;
            m[n] = mkv2(__builtin_fmaf(mr, mr, -(mi * mi)), 2.0f * mr * mi);
        }
    }

    // --- wave-synchronous Hillis-Steele over 64 lanes (in-register).
    //     Wave 1 accumulates W = A^(llane+1) for the cross-wave correction.
    const bool w1 = (tid >= 64);
    v2 W[kN];
#pragma unroll
    for (int n = 0; n < kN; n++) W[n] = m[n];     // A^1
#pragma unroll
    for (int k = 0; k < 6; k++) {
        const int s = 1 << k;
#pragma unroll
        for (int n = 0; n < kN; n++) {
            float tr = __shfl_up(u[n].x, (unsigned)s, 64);
            float ti = __shfl_up(u[n].y, (unsigned)s, 64);
            if (llane >= s) {
                u[n].x = __builtin_fmaf(m[n].x, tr,
                          __builtin_fmaf(-m[n].y, ti, u[n].x));
                u[n].y = __builtin_fmaf(m[n].x, ti,
                          __builtin_fmaf( m[n].y, tr, u[n].y));
            }
        }
        if (w1 && (llane & s)) {
#pragma unroll
            for (int n = 0; n < kN; n++) {
                float wr = W[n].x, wi = W[n].y;
                W[n].x = __builtin_fmaf(wr, m[n].x, -(wi * m[n].y));
                W[n].y = __builtin_fmaf(wr, m[n].y,  wi * m[n].x);
            }
        }
        if (k < 5) {                       // last squaring unneeded
#pragma unroll
            for (int n = 0; n < kN; n++) {
                float mr = m[n].x, mi = m[n].y;
                m[n] = mkv2(__builtin_fmaf(mr, mr, -(mi * mi)), 2.0f * mr * mi);
            }
        }
    }

    // --- re-issue the x burst for phase 3 NOW (L2/L3-resident: FETCH counter
    //     shows 34MB for a 64MB input). The loads drain while we do the
    //     publish barrier, cross-wave correction, hout write and coeff
    //     rebuild (~300+ cycles of cover).
    float4 tb[8];
#pragma unroll
    for (int k = 0; k < 8; k++) tb[k] = xp[k];

    // --- cross-wave combine: publish wave-0 lane-63 state, one barrier.
    if (tid == 63) {
#pragma unroll
        for (int n = 0; n < kN; n++) { pubr[n] = u[n].x; pubi[n] = u[n].y; }
    }
    __syncthreads();                       // barrier #2
    if (w1) {
#pragma unroll
        for (int n = 0; n < kN; n++) {
            float pr = pubr[n], pi = pubi[n];
            u[n].x = __builtin_fmaf(W[n].x, pr,
                      __builtin_fmaf(-W[n].y, pi, u[n].x));
            u[n].y = __builtin_fmaf(W[n].x, pi,
                      __builtin_fmaf( W[n].y, pr, u[n].y));
        }
    }

    // --- final state (tid 127 inclusive) -> hout, h = p*u
    if (tid == kT - 1) {
        float4* hp = (float4*)(hout + (size_t)row * (kN * 2));
#pragma unroll
        for (int n = 0; n < kN; n += 2)
            hp[n >> 1] = make_float4(cp[n] * u[n].x,         cp[n] * u[n].y,
                                     cp[n + 1] * u[n + 1].x, cp[n + 1] * u[n + 1].y);
    }

    // --- exclusive prefix: shift down one lane; lane 0 of wave 1 takes the
    //     published wave-0 final; lane 0 of wave 0 takes zero.
#pragma unroll
    for (int n = 0; n < kN; n++) {
        float pr = __shfl_up(u[n].x, 1, 64);
        float pi = __shfl_up(u[n].y, 1, 64);
        u[n] = mkv2(pr, pi);
    }
    if (llane == 0) {
#pragma unroll
        for (int n = 0; n < kN; n++)
            u[n] = (tid == 0) ? mkv2(0.0f, 0.0f) : mkv2(pubr[n], pubi[n]);
    }

    // --- unpack the reloaded x (static indexing only)
#pragma unroll
    for (int k = 0; k < 8; k++) {
        xs[4*k+0] = tb[k].x; xs[4*k+1] = tb[k].y;
        xs[4*k+2] = tb[k].z; xs[4*k+3] = tb[k].w;
    }

    // --- phase 3: rebuild coefficient regs, re-run chunk, emit y.
    v2 qx[kN], qy[kN], g[kN];
#pragma unroll
    for (int n = 0; n < kN; n++) {
        qx[n] = mkv2(cqr[n],  cqr[n]);
        qy[n] = mkv2(-cqi[n], cqi[n]);
        g[n]  = mkv2(cgr[n],  cgi[n]);
    }
    const float om = omega[d];

    float ys[kCH];
#pragma unroll
    for (int j = 0; j < kCH; j++) {
        float xj = xs[j];
        v2 xv = mkv2(xj, 0.0f);
        v2 acc0 = mkv2(0.0f, 0.0f), acc1 = mkv2(0.0f, 0.0f);
        v2 acc2 = mkv2(0.0f, 0.0f), acc3 = mkv2(0.0f, 0.0f);
#pragma unroll
        for (int n = 0; n < kN; n += 4) {
            v2 a;
            a = v2fma(qx[n],   u[n],   xv);
            u[n]   = v2fma(qy[n],   mkv2(u[n].y,   u[n].x),   a);
            acc0   = v2fma(g[n],    u[n],   acc0);
            a = v2fma(qx[n+1], u[n+1], xv);
            u[n+1] = v2fma(qy[n+1], mkv2(u[n+1].y, u[n+1].x), a);
            acc1   = v2fma(g[n+1],  u[n+1], acc1);
            a = v2fma(qx[n+2], u[n+2], xv);
            u[n+2] = v2fma(qy[n+2], mkv2(u[n+2].y, u[n+2].x), a);
            acc2   = v2fma(g[n+2],  u[n+2], acc2);
            a = v2fma(qx[n+3], u[n+3], xv);
            u[n+3] = v2fma(qy[n+3], mkv2(u[n+3].y, u[n+3].x), a);
            acc3   = v2fma(g[n+3],  u[n+3], acc3);
        }
        v2 s = (acc0 + acc1) + (acc2 + acc3);
        ys[j] = s.x + s.y + om * xj;
    }

    // burst stores (8 back-to-back dwordx4 = 128 B/lane)
    float4* yp = (float4*)(y + (size_t)row * kL + (size_t)tid * kCH);
#pragma unroll
    for (int k = 0; k < 8; k++)
        yp[k] = make_float4(ys[4*k+0], ys[4*k+1], ys[4*k+2], ys[4*k+3]);
}

extern "C" void kernel_launch(void* const* d_in, const int* in_sizes, int n_in,
                              void* d_out, int out_size, void* d_ws, size_t ws_size,
                              hipStream_t stream) {
    const float* x     = (const float*)d_in[0];
    const float* alpha = (const float*)d_in[1];
    const float* delta = (const float*)d_in[2];
    const float* theta = (const float*)d_in[3];
    const float* gamma = (const float*)d_in[4];
    const float* omega = (const float*)d_in[5];
    float* y    = (float*)d_out;
    float* hout = y + (size_t)kB * kD * kL;      // (B,D,N,2) after y

    fused_kernel<<<kB * kD, kT, 0, stream>>>(x, alpha, delta, theta, gamma,
                                             omega, y, hout);
}

// Round 7
// 183.918 us; speedup vs baseline: 2.1452x; 1.0157x over previous
//
#include <hip/hip_runtime.h>
#include <math.h>

// ComplexEMA fused single-kernel (R8 resubmit -- Round-6 bench never ran:
// GPU acquisition timeout. Same kernel so the occupancy A/B actually runs).
// y[b,d,t] = Re(sum_n gam_dn * h_dn[t]) + omega_d * x[b,d,t]
// h[t] = q*h[t-1] + p*x[t];  substitution u = h/p:  u' = q*u + x, gam' = p*gam.
//
// Occupancy experiment: R4/R6/R7 all show OccupancyPercent ~18% (1.5 waves/
// SIMD resident) at VGPR~116 (cap 4/SIMD), VALUBusy 56-62% -> ~40% of issue
// slots idle. R5 (VGPR 64, cap 8/SIMD) showed 39% occ. Resident waves ~ 37%
// of cap in both => hypothesis: residency is limited per-BLOCK (~3 blocks/CU
// sustained). R8 packs 2 independent rows into one 256-thread block (4 waves)
// with unchanged per-thread code: if ~3 blocks/CU persists, resident waves
// double to 3/SIMD and the latency windows get covered.
//
// Per row (128 threads = 2 waves): each thread owns a 32-step chunk, x burst-
// loaded to registers (8 dwordx4 = 128B/lane). Phase 1: local recurrence from
// zero -> chunk end-state. Scan: 6-round __shfl_up Hillis-Steele per wave
// (A=q^32 doubling), W=A^(llane+1) on the row's wave 1, one LDS publish +
// barrier for the cross-wave combine. Phase 3: x re-read from global (L3-hot:
// FETCH=34-40MB vs 64MB logical), recurrence re-run from exclusive prefix,
// y emitted with 128B/lane burst stores.

constexpr int kD = 2048, kN = 16, kB = 2, kL = 4096;
constexpr int kT   = 256;           // threads per block = 2 rows x 128
constexpr int kTR  = 128;           // threads per row, 2 waves
constexpr int kCH  = kL / kTR;      // 32 timesteps per thread
constexpr float kSCALE = 0.25f;     // sqrt(1/16)

typedef float v2 __attribute__((ext_vector_type(2)));

static __device__ __forceinline__ v2 mkv2(float a, float b) {
    v2 r; r.x = a; r.y = b; return r;
}

static __device__ __forceinline__ v2 v2fma(v2 a, v2 b, v2 c) {
#if __has_builtin(__builtin_elementwise_fma)
    return __builtin_elementwise_fma(a, b, c);
#else
    v2 r;
    r.x = __builtin_fmaf(a.x, b.x, c.x);
    r.y = __builtin_fmaf(a.y, b.y, c.y);
    return r;
#endif
}

__global__ __launch_bounds__(kT, 2) void fused_kernel(
    const float* __restrict__ x,     const float* __restrict__ alpha,
    const float* __restrict__ delta, const float* __restrict__ theta,
    const float* __restrict__ gamma, const float* __restrict__ omega,
    float* __restrict__ y,           float* __restrict__ hout)
{
    __shared__ float cqr[2][kN], cqi[2][kN], cgr[2][kN], cgi[2][kN], cp[2][kN];
    __shared__ float pubr[2][kN], pubi[2][kN];   // per-row wave-0 publish

    const int tid   = threadIdx.x;
    const int rl    = tid >> 7;            // row-local 0/1
    const int t2    = tid & (kTR - 1);     // thread index within row
    const int row   = blockIdx.x * 2 + rl; // b*kD + d
    const int d     = row & (kD - 1);
    const int llane = tid & 63;
    const bool w1   = (t2 >= 64);          // row's second wave

    const float4* xp = (const float4*)(x + (size_t)row * kL + (size_t)t2 * kCH);

    // --- burst-load 32 x samples to registers (8 back-to-back dwordx4 =
    //     128 B/lane). Issued first; latency hides under coeff compute.
    float xs[kCH];
    {
        float4 tb0[8];
#pragma unroll
        for (int k = 0; k < 8; k++) tb0[k] = xp[k];
#pragma unroll
        for (int k = 0; k < 8; k++) {
            xs[4*k+0] = tb0[k].x; xs[4*k+1] = tb0[k].y;
            xs[4*k+2] = tb0[k].z; xs[4*k+3] = tb0[k].w;
        }
    }

    // --- coefficients (threads 0..15 of each row, one n each)
    if (t2 < kN) {
        int n = t2, i = d * kN + n;
        float p  = 1.0f / (1.0f + expf(-alpha[i]));
        float dd = 1.0f / (1.0f + expf(-delta[i]));
        float th = 1.0f / (1.0f + expf(-theta[d]));
        float phi = (float)(n + 1) * th * 0.39269908169872414f;  // 2*pi/16
        float r = 1.0f - p * dd;
        float s, c;
        sincosf(phi, &s, &c);
        cqr[rl][n] = r * c;
        cqi[rl][n] = r * s;
        cgr[rl][n] = p * kSCALE * gamma[2 * i];
        cgi[rl][n] = -(p * kSCALE * gamma[2 * i + 1]);
        cp[rl][n]  = p;
    }
    __syncthreads();                       // barrier #1 (coeff visibility)

    // --- phase 1: local recurrence from zero init (first step peeled:
    //     u = q*0 + x0 = (x0, 0)). x consumed from registers.
    v2 u[kN];
    {
        v2 qx[kN], qy[kN];
#pragma unroll
        for (int n = 0; n < kN; n++) {
            qx[n] = mkv2(cqr[rl][n],  cqr[rl][n]);
            qy[n] = mkv2(-cqi[rl][n], cqi[rl][n]);
        }
#pragma unroll
        for (int n = 0; n < kN; n++) u[n] = mkv2(xs[0], 0.0f);
#pragma unroll
        for (int j = 1; j < kCH; j++) {
            v2 xv = mkv2(xs[j], 0.0f);
#pragma unroll
            for (int n = 0; n < kN; n++) {
                v2 a = v2fma(qx[n], u[n], xv);
                u[n] = v2fma(qy[n], mkv2(u[n].y, u[n].x), a);
            }
        }
    }   // qx/qy and xs dead here

    // --- A = q^32 via 5 complex squarings
    v2 m[kN];
#pragma unroll
    for (int n = 0; n < kN; n++) m[n] = mkv2(cqr[rl][n], cqi[rl][n]);
#pragma unroll
    for (int k = 0; k < 5; k++) {
#pragma unroll
        for (int n = 0; n < kN; n++) {
            float mr = m[n].x, mi = m[n].y;
            m[n] = mkv2(__builtin_fmaf(mr, mr, -(mi * mi)), 2.0f * mr * mi);
        }
    }

    // --- wave-synchronous Hillis-Steele over 64 lanes (in-register).
    //     The row's wave 1 accumulates W = A^(llane+1) for the cross-wave fix.
    v2 W[kN];
#pragma unroll
    for (int n = 0; n < kN; n++) W[n] = m[n];     // A^1
#pragma unroll
    for (int k = 0; k < 6; k++) {
        const int s = 1 << k;
#pragma unroll
        for (int n = 0; n < kN; n++) {
            float tr = __shfl_up(u[n].x, (unsigned)s, 64);
            float ti = __shfl_up(u[n].y, (unsigned)s, 64);
            if (llane >= s) {
                u[n].x = __builtin_fmaf(m[n].x, tr,
                          __builtin_fmaf(-m[n].y, ti, u[n].x));
                u[n].y = __builtin_fmaf(m[n].x, ti,
                          __builtin_fmaf( m[n].y, tr, u[n].y));
            }
        }
        if (w1 && (llane & s)) {
#pragma unroll
            for (int n = 0; n < kN; n++) {
                float wr = W[n].x, wi = W[n].y;
                W[n].x = __builtin_fmaf(wr, m[n].x, -(wi * m[n].y));
                W[n].y = __builtin_fmaf(wr, m[n].y,  wi * m[n].x);
            }
        }
        if (k < 5) {                       // last squaring unneeded
#pragma unroll
            for (int n = 0; n < kN; n++) {
                float mr = m[n].x, mi = m[n].y;
                m[n] = mkv2(__builtin_fmaf(mr, mr, -(mi * mi)), 2.0f * mr * mi);
            }
        }
    }

    // --- re-issue the x burst for phase 3 NOW (L2/L3-resident). Drains while
    //     we do the publish barrier, correction, hout write, coeff rebuild.
    float4 tb[8];
#pragma unroll
    for (int k = 0; k < 8; k++) tb[k] = xp[k];

    // --- cross-wave combine: publish each row's wave-0 lane-63 state.
    if (t2 == 63) {
#pragma unroll
        for (int n = 0; n < kN; n++) { pubr[rl][n] = u[n].x; pubi[rl][n] = u[n].y; }
    }
    __syncthreads();                       // barrier #2
    if (w1) {
#pragma unroll
        for (int n = 0; n < kN; n++) {
            float pr = pubr[rl][n], pi = pubi[rl][n];
            u[n].x = __builtin_fmaf(W[n].x, pr,
                      __builtin_fmaf(-W[n].y, pi, u[n].x));
            u[n].y = __builtin_fmaf(W[n].x, pi,
                      __builtin_fmaf( W[n].y, pr, u[n].y));
        }
    }

    // --- final state (row thread 127, inclusive) -> hout, h = p*u
    if (t2 == kTR - 1) {
        float4* hp = (float4*)(hout + (size_t)row * (kN * 2));
#pragma unroll
        for (int n = 0; n < kN; n += 2)
            hp[n >> 1] = make_float4(cp[rl][n] * u[n].x,         cp[rl][n] * u[n].y,
                                     cp[rl][n + 1] * u[n + 1].x, cp[rl][n + 1] * u[n + 1].y);
    }

    // --- exclusive prefix: shift down one lane; each row's wave-1 lane 0
    //     takes the published wave-0 final; row thread 0 takes zero.
#pragma unroll
    for (int n = 0; n < kN; n++) {
        float pr = __shfl_up(u[n].x, 1, 64);
        float pi = __shfl_up(u[n].y, 1, 64);
        u[n] = mkv2(pr, pi);
    }
    if (llane == 0) {
#pragma unroll
        for (int n = 0; n < kN; n++)
            u[n] = (t2 == 0) ? mkv2(0.0f, 0.0f) : mkv2(pubr[rl][n], pubi[rl][n]);
    }

    // --- unpack the reloaded x (static indexing only)
#pragma unroll
    for (int k = 0; k < 8; k++) {
        xs[4*k+0] = tb[k].x; xs[4*k+1] = tb[k].y;
        xs[4*k+2] = tb[k].z; xs[4*k+3] = tb[k].w;
    }

    // --- phase 3: rebuild coefficient regs, re-run chunk, emit y.
    v2 qx[kN], qy[kN], g[kN];
#pragma unroll
    for (int n = 0; n < kN; n++) {
        qx[n] = mkv2(cqr[rl][n],  cqr[rl][n]);
        qy[n] = mkv2(-cqi[rl][n], cqi[rl][n]);
        g[n]  = mkv2(cgr[rl][n],  cgi[rl][n]);
    }
    const float om = omega[d];

    float ys[kCH];
#pragma unroll
    for (int j = 0; j < kCH; j++) {
        float xj = xs[j];
        v2 xv = mkv2(xj, 0.0f);
        v2 acc0 = mkv2(0.0f, 0.0f), acc1 = mkv2(0.0f, 0.0f);
        v2 acc2 = mkv2(0.0f, 0.0f), acc3 = mkv2(0.0f, 0.0f);
#pragma unroll
        for (int n = 0; n < kN; n += 4) {
            v2 a;
            a = v2fma(qx[n],   u[n],   xv);
            u[n]   = v2fma(qy[n],   mkv2(u[n].y,   u[n].x),   a);
            acc0   = v2fma(g[n],    u[n],   acc0);
            a = v2fma(qx[n+1], u[n+1], xv);
            u[n+1] = v2fma(qy[n+1], mkv2(u[n+1].y, u[n+1].x), a);
            acc1   = v2fma(g[n+1],  u[n+1], acc1);
            a = v2fma(qx[n+2], u[n+2], xv);
            u[n+2] = v2fma(qy[n+2], mkv2(u[n+2].y, u[n+2].x), a);
            acc2   = v2fma(g[n+2],  u[n+2], acc2);
            a = v2fma(qx[n+3], u[n+3], xv);
            u[n+3] = v2fma(qy[n+3], mkv2(u[n+3].y, u[n+3].x), a);
            acc3   = v2fma(g[n+3],  u[n+3], acc3);
        }
        v2 s = (acc0 + acc1) + (acc2 + acc3);
        ys[j] = s.x + s.y + om * xj;
    }

    // burst stores (8 back-to-back dwordx4 = 128 B/lane)
    float4* yp = (float4*)(y + (size_t)row * kL + (size_t)t2 * kCH);
#pragma unroll
    for (int k = 0; k < 8; k++)
        yp[k] = make_float4(ys[4*k+0], ys[4*k+1], ys[4*k+2], ys[4*k+3]);
}

extern "C" void kernel_launch(void* const* d_in, const int* in_sizes, int n_in,
                              void* d_out, int out_size, void* d_ws, size_t ws_size,
                              hipStream_t stream) {
    const float* x     = (const float*)d_in[0];
    const float* alpha = (const float*)d_in[1];
    const float* delta = (const float*)d_in[2];
    const float* theta = (const float*)d_in[3];
    const float* gamma = (const float*)d_in[4];
    const float* omega = (const float*)d_in[5];
    float* y    = (float*)d_out;
    float* hout = y + (size_t)kB * kD * kL;      // (B,D,N,2) after y

    fused_kernel<<<(kB * kD) / 2, kT, 0, stream>>>(x, alpha, delta, theta,
                                                   gamma, omega, y, hout);
}